// Round 1
// baseline (2609.592 us; speedup 1.0000x reference)
//
#include <hip/hip_runtime.h>
#include <math.h>

// Problem constants (from reference)
constexpr int kB  = 16;
constexpr int kN  = 512;
constexpr int kD  = 256;
constexpr int kH  = 8;
constexpr int kDK = 32;
constexpr int kL  = 4;

// ---------------- block reduction helpers (256 threads = 4 waves) ----------
__device__ __forceinline__ float blockReduceSum(float v, float* sh) {
    #pragma unroll
    for (int o = 32; o > 0; o >>= 1) v += __shfl_down(v, o, 64);
    int lane = threadIdx.x & 63, w = threadIdx.x >> 6;
    __syncthreads();
    if (lane == 0) sh[w] = v;
    __syncthreads();
    return sh[0] + sh[1] + sh[2] + sh[3];
}

__device__ __forceinline__ float blockReduceMax(float v, float* sh) {
    #pragma unroll
    for (int o = 32; o > 0; o >>= 1) v = fmaxf(v, __shfl_down(v, o, 64));
    int lane = threadIdx.x & 63, w = threadIdx.x >> 6;
    __syncthreads();
    if (lane == 0) sh[w] = v;
    __syncthreads();
    return fmaxf(fmaxf(sh[0], sh[1]), fmaxf(sh[2], sh[3]));
}

// ---------------- pc = 0.3*softmax(mask? -dist : -inf) + 0.4*adj/rowsum ----
// one block per (b, q) row; threads cover k = t and t+256
__global__ __launch_bounds__(256) void pc_kernel(const float* __restrict__ adj,
                                                 const float* __restrict__ dist,
                                                 const int* __restrict__ mask,
                                                 float* __restrict__ pc) {
    __shared__ float sh[4];
    int row = blockIdx.x;            // b*kN + q
    int b = row >> 9;
    int t = threadIdx.x;
    const float* dr = dist + (size_t)row * kN;
    const float* ar = adj + (size_t)row * kN;
    const int* mr = mask + b * kN;
    float d0 = dr[t], d1 = dr[t + 256];
    float a0 = ar[t], a1 = ar[t + 256];
    int m0 = mr[t], m1 = mr[t + 256];
    float s0 = m0 ? -d0 : -INFINITY;
    float s1 = m1 ? -d1 : -INFINITY;
    float mx = blockReduceMax(fmaxf(s0, s1), sh);
    float e0 = __expf(s0 - mx);
    float e1 = __expf(s1 - mx);
    float sum  = blockReduceSum(e0 + e1, sh);
    float asum = blockReduceSum(a0 + a1, sh);
    float w_d = 0.3f / sum;
    float w_a = 0.4f / (asum + 1e-6f);
    float* pr = pc + (size_t)row * kN;
    pr[t]       = e0 * w_d + a0 * w_a;
    pr[t + 256] = e1 * w_d + a1 * w_a;
}

// ---------------- LayerNorm (ddof=1, eps added to std) ---------------------
__global__ __launch_bounds__(256) void ln_kernel(const float* __restrict__ x,
                                                 const float* __restrict__ ga,
                                                 const float* __restrict__ gb,
                                                 float* __restrict__ y) {
    __shared__ float sh[4];
    int row = blockIdx.x, t = threadIdx.x;
    float v = x[(size_t)row * kD + t];
    float m = blockReduceSum(v, sh) * (1.0f / kD);
    float dd = v - m;
    float var = blockReduceSum(dd * dd, sh) * (1.0f / (kD - 1));
    float s = sqrtf(var);
    y[(size_t)row * kD + t] = ga[t] * dd / (s + 1e-6f) + gb[t];
}

// ---------------- generic 8192x256x256 fp32 GEMM with fused epilogues ------
enum { EPI_PLAIN = 0, EPI_QKV = 1, EPI_RESID = 2, EPI_LRELU = 3, EPI_RESID_LRELU = 4 };

template <int EPI>
__global__ __launch_bounds__(256) void gemm_kernel(const float* __restrict__ A,
                                                   const float* __restrict__ W,
                                                   const float* __restrict__ bias,
                                                   const float* __restrict__ resid,
                                                   float* __restrict__ C) {
    __shared__ float As[16][68];   // A tile transposed [k][m], pad 68 -> 2-way max on write
    __shared__ float Bs[16][64];   // W tile [k][n]
    int t = threadIdx.x;
    int tx = t & 15, ty = t >> 4;
    int m0 = blockIdx.x * 64, n0 = blockIdx.y * 64;
    float acc[4][4] = {{0.f}};
    for (int k0 = 0; k0 < kD; k0 += 16) {
        #pragma unroll
        for (int i = 0; i < 4; i++) {
            int flat = t + i * 256;
            int r = flat >> 4, c = flat & 15;
            As[c][r] = A[(size_t)(m0 + r) * kD + k0 + c];
        }
        #pragma unroll
        for (int i = 0; i < 4; i++) {
            int flat = t + i * 256;
            int kk = flat >> 6, n = flat & 63;
            Bs[kk][n] = W[(size_t)(k0 + kk) * kD + n0 + n];
        }
        __syncthreads();
        #pragma unroll
        for (int k = 0; k < 16; k++) {
            float a[4], b2[4];
            #pragma unroll
            for (int i = 0; i < 4; i++) a[i] = As[k][ty * 4 + i];
            #pragma unroll
            for (int j = 0; j < 4; j++) b2[j] = Bs[k][tx * 4 + j];
            #pragma unroll
            for (int i = 0; i < 4; i++)
                #pragma unroll
                for (int j = 0; j < 4; j++)
                    acc[i][j] = fmaf(a[i], b2[j], acc[i][j]);
        }
        __syncthreads();
    }
    #pragma unroll
    for (int i = 0; i < 4; i++) {
        int m = m0 + ty * 4 + i;
        #pragma unroll
        for (int j = 0; j < 4; j++) {
            int n = n0 + tx * 4 + j;
            float v = acc[i][j] + bias[n];
            if (EPI == EPI_QKV) {
                // scatter to (B,H,N,DK)
                int b = m >> 9, nr = m & 511;
                int hh = n >> 5, dk = n & 31;
                C[(((size_t)(b * kH + hh)) * kN + nr) * kDK + dk] = v;
            } else if (EPI == EPI_RESID) {
                C[(size_t)m * kD + n] = resid[(size_t)m * kD + n] + v;
            } else if (EPI == EPI_LRELU) {
                C[(size_t)m * kD + n] = v > 0.f ? v : 0.1f * v;
            } else if (EPI == EPI_RESID_LRELU) {
                float lv = v > 0.f ? v : 0.1f * v;
                C[(size_t)m * kD + n] = resid[(size_t)m * kD + n] + lv;
            } else {
                C[(size_t)m * kD + n] = v;
            }
        }
    }
}

// ---------------- attention: one block per (b,h,16 q-rows) ------------------
// phase 1: scores + masked softmax + mix with pc  -> Ps (LDS)
// phase 2: att = Ps @ V
__global__ __launch_bounds__(256) void attn_kernel(const float* __restrict__ q,
                                                   const float* __restrict__ k,
                                                   const float* __restrict__ v,
                                                   const float* __restrict__ pc,
                                                   const int* __restrict__ mask,
                                                   float* __restrict__ att) {
    __shared__ float qs[16][36];     // q tile, padded & 16B-aligned rows
    __shared__ float Ps[16][520];    // probability rows, padded (bank spread)
    int blk = blockIdx.x;
    int qt = blk & 31;               // N/16 = 32 q-tiles
    int bh = blk >> 5;
    int b = bh >> 3;
    int h = bh & 7;
    int t = threadIdx.x;
    int lane = t & 63, w = t >> 6;

    const float* qbase = q + ((size_t)bh * kN + qt * 16) * kDK;
    #pragma unroll
    for (int i = 0; i < 2; i++) {
        int flat = t + i * 256;
        qs[flat >> 5][flat & 31] = qbase[flat];
    }
    __syncthreads();

    const float* kbase = k + (size_t)bh * kN * kDK;
    const int* mb = mask + b * kN;
    float s[4][8];  // rows w*4+r, cols lane + 64*j
    #pragma unroll
    for (int j = 0; j < 8; j++) {
        int n = lane + j * 64;
        const float4* kr = (const float4*)(kbase + (size_t)n * kDK);
        float4 kk[8];
        #pragma unroll
        for (int d4 = 0; d4 < 8; d4++) kk[d4] = kr[d4];
        #pragma unroll
        for (int r = 0; r < 4; r++) {
            const float4* qq = (const float4*)&qs[w * 4 + r][0];
            float acc = 0.f;
            #pragma unroll
            for (int d4 = 0; d4 < 8; d4++) {
                float4 qv = qq[d4];
                acc = fmaf(qv.x, kk[d4].x, acc);
                acc = fmaf(qv.y, kk[d4].y, acc);
                acc = fmaf(qv.z, kk[d4].z, acc);
                acc = fmaf(qv.w, kk[d4].w, acc);
            }
            s[r][j] = acc;
        }
    }
    const float scale = 0.17677669529663689f;  // 1/sqrt(32)
    #pragma unroll
    for (int j = 0; j < 8; j++) {
        int n = lane + j * 64;
        int mm = mb[n];
        #pragma unroll
        for (int r = 0; r < 4; r++)
            s[r][j] = mm ? s[r][j] * scale : -1e12f;   // NEG_INF
    }
    #pragma unroll
    for (int r = 0; r < 4; r++) {
        int qi = w * 4 + r;
        float mx = s[r][0];
        #pragma unroll
        for (int j = 1; j < 8; j++) mx = fmaxf(mx, s[r][j]);
        #pragma unroll
        for (int o = 32; o > 0; o >>= 1) mx = fmaxf(mx, __shfl_xor(mx, o, 64));
        float e[8];
        float sum = 0.f;
        #pragma unroll
        for (int j = 0; j < 8; j++) { e[j] = __expf(s[r][j] - mx); sum += e[j]; }
        #pragma unroll
        for (int o = 32; o > 0; o >>= 1) sum += __shfl_xor(sum, o, 64);
        float inv = 0.3f / sum;
        const float* pcr = pc + ((size_t)b * kN + qt * 16 + qi) * kN;
        #pragma unroll
        for (int j = 0; j < 8; j++) {
            int n = lane + j * 64;
            Ps[qi][n] = e[j] * inv + pcr[n];
        }
    }
    __syncthreads();

    // phase 2: P (16x512) @ V (512x32); thread (g,d): g=t>>5 handles rows 2g,2g+1
    int d = t & 31, g = t >> 5;
    const float* vbase = v + (size_t)bh * kN * kDK;
    float acc0 = 0.f, acc1 = 0.f;
    int qi0 = g * 2, qi1 = qi0 + 1;
    for (int n = 0; n < kN; n += 4) {
        #pragma unroll
        for (int u = 0; u < 4; u++) {
            float vv = vbase[(size_t)(n + u) * kDK + d];
            acc0 = fmaf(Ps[qi0][n + u], vv, acc0);
            acc1 = fmaf(Ps[qi1][n + u], vv, acc1);
        }
    }
    size_t row0 = (size_t)b * kN + qt * 16 + qi0;
    att[row0 * kD + h * kDK + d]       = acc0;
    att[(row0 + 1) * kD + h * kDK + d] = acc1;
}

// ---------------- host launcher --------------------------------------------
extern "C" void kernel_launch(void* const* d_in, const int* in_sizes, int n_in,
                              void* d_out, int out_size, void* d_ws, size_t ws_size,
                              hipStream_t stream) {
    const float* x    = (const float*)d_in[0];
    const int*   mask = (const int*)d_in[1];
    const float* adj  = (const float*)d_in[2];
    const float* dist = (const float*)d_in[3];
    // d_in[4] = edges_att (unused by reference)
    const float* Wq = (const float*)d_in[5];  const float* bq = (const float*)d_in[6];
    const float* Wk = (const float*)d_in[7];  const float* bk = (const float*)d_in[8];
    const float* Wv = (const float*)d_in[9];  const float* bv = (const float*)d_in[10];
    const float* Wo = (const float*)d_in[11]; const float* bo = (const float*)d_in[12];
    const float* Wf1 = (const float*)d_in[13]; const float* bf1 = (const float*)d_in[14];
    const float* Wf2 = (const float*)d_in[15]; const float* bf2 = (const float*)d_in[16];
    const float* ln1a = (const float*)d_in[17]; const float* ln1b = (const float*)d_in[18];
    const float* ln2a = (const float*)d_in[19]; const float* ln2b = (const float*)d_in[20];
    const float* lnfa = (const float*)d_in[21]; const float* lnfb = (const float*)d_in[22];

    const size_t rows = (size_t)kB * kN;          // 8192
    const size_t actN = rows * kD;                // 2,097,152 elems
    float* ws = (float*)d_ws;
    float* pc   = ws;                                  // B*N*N
    float* xc   = pc + (size_t)kB * kN * kN;
    float* h    = xc + actN;
    float* qb   = h + actN;
    float* kb   = qb + actN;
    float* vb   = kb + actN;
    float* attb = vb + actN;
    float* h2   = qb;  // alias: q dead once attention done

    hipMemcpyAsync(xc, x, actN * sizeof(float), hipMemcpyDeviceToDevice, stream);
    pc_kernel<<<kB * kN, 256, 0, stream>>>(adj, dist, mask, pc);

    dim3 gg(128, 4);  // M/64 x 256/64
    for (int i = 0; i < kL; i++) {
        const size_t wOff = (size_t)i * kD * kD;
        const size_t bOff = (size_t)i * kD;
        ln_kernel<<<rows, 256, 0, stream>>>(xc, ln1a + bOff, ln1b + bOff, h);
        gemm_kernel<EPI_QKV><<<gg, 256, 0, stream>>>(h, Wq + wOff, bq + bOff, nullptr, qb);
        gemm_kernel<EPI_QKV><<<gg, 256, 0, stream>>>(h, Wk + wOff, bk + bOff, nullptr, kb);
        gemm_kernel<EPI_QKV><<<gg, 256, 0, stream>>>(h, Wv + wOff, bv + bOff, nullptr, vb);
        attn_kernel<<<kB * kH * (kN / 16), 256, 0, stream>>>(qb, kb, vb, pc, mask, attb);
        gemm_kernel<EPI_RESID><<<gg, 256, 0, stream>>>(attb, Wo + wOff, bo + bOff, xc, xc);
        ln_kernel<<<rows, 256, 0, stream>>>(xc, ln2a + bOff, ln2b + bOff, h);
        gemm_kernel<EPI_LRELU><<<gg, 256, 0, stream>>>(h, Wf1 + wOff, bf1 + bOff, nullptr, h2);
        gemm_kernel<EPI_RESID_LRELU><<<gg, 256, 0, stream>>>(h2, Wf2 + wOff, bf2 + bOff, xc, xc);
    }
    ln_kernel<<<rows, 256, 0, stream>>>(xc, lnfa, lnfb, (float*)d_out);
}

// Round 2
// 819.688 us; speedup vs baseline: 3.1836x; 3.1836x over previous
//
#include <hip/hip_runtime.h>
#include <hip/hip_bf16.h>
#include <math.h>

// Problem constants (from reference)
constexpr int kB  = 16;
constexpr int kN  = 512;
constexpr int kD  = 256;
constexpr int kH  = 8;
constexpr int kDK = 32;
constexpr int kL  = 4;

using bf16 = __hip_bfloat16;
using short8 = __attribute__((ext_vector_type(8))) short;   // 8 bf16 = 4 VGPR
using floatx4 = __attribute__((ext_vector_type(4))) float;  // MFMA C/D frag

// ---------------- block reduction helpers (256 threads = 4 waves) ----------
__device__ __forceinline__ float blockReduceSum(float v, float* sh) {
    #pragma unroll
    for (int o = 32; o > 0; o >>= 1) v += __shfl_down(v, o, 64);
    int lane = threadIdx.x & 63, w = threadIdx.x >> 6;
    __syncthreads();
    if (lane == 0) sh[w] = v;
    __syncthreads();
    return sh[0] + sh[1] + sh[2] + sh[3];
}

__device__ __forceinline__ float blockReduceMax(float v, float* sh) {
    #pragma unroll
    for (int o = 32; o > 0; o >>= 1) v = fmaxf(v, __shfl_down(v, o, 64));
    int lane = threadIdx.x & 63, w = threadIdx.x >> 6;
    __syncthreads();
    if (lane == 0) sh[w] = v;
    __syncthreads();
    return fmaxf(fmaxf(sh[0], sh[1]), fmaxf(sh[2], sh[3]));
}

// ---------------- pc = 0.3*softmax(mask? -dist : -inf) + 0.4*adj/rowsum ----
// one block per (b, q) row; threads cover k = t and t+256.  Output bf16.
__global__ __launch_bounds__(256) void pc_kernel(const float* __restrict__ adj,
                                                 const float* __restrict__ dist,
                                                 const int* __restrict__ mask,
                                                 bf16* __restrict__ pcb) {
    __shared__ float sh[4];
    int row = blockIdx.x;            // b*kN + q
    int b = row >> 9;
    int t = threadIdx.x;
    const float* dr = dist + (size_t)row * kN;
    const float* ar = adj + (size_t)row * kN;
    const int* mr = mask + b * kN;
    float d0 = dr[t], d1 = dr[t + 256];
    float a0 = ar[t], a1 = ar[t + 256];
    int m0 = mr[t], m1 = mr[t + 256];
    float s0 = m0 ? -d0 : -INFINITY;
    float s1 = m1 ? -d1 : -INFINITY;
    float mx = blockReduceMax(fmaxf(s0, s1), sh);
    float e0 = __expf(s0 - mx);
    float e1 = __expf(s1 - mx);
    float sum  = blockReduceSum(e0 + e1, sh);
    float asum = blockReduceSum(a0 + a1, sh);
    float w_d = 0.3f / sum;
    float w_a = 0.4f / (asum + 1e-6f);
    bf16* pr = pcb + (size_t)row * kN;
    pr[t]       = bf16(e0 * w_d + a0 * w_a);
    pr[t + 256] = bf16(e1 * w_d + a1 * w_a);
}

// ---------------- LayerNorm (ddof=1, eps added to std) ---------------------
__global__ __launch_bounds__(256) void ln_kernel(const float* __restrict__ x,
                                                 const float* __restrict__ ga,
                                                 const float* __restrict__ gb,
                                                 float* __restrict__ y) {
    __shared__ float sh[4];
    int row = blockIdx.x, t = threadIdx.x;
    float v = x[(size_t)row * kD + t];
    float m = blockReduceSum(v, sh) * (1.0f / kD);
    float dd = v - m;
    float var = blockReduceSum(dd * dd, sh) * (1.0f / (kD - 1));
    float s = sqrtf(var);
    y[(size_t)row * kD + t] = ga[t] * dd / (s + 1e-6f) + gb[t];
}

// ---------------- generic 8192x256x256 fp32 GEMM with fused epilogues ------
enum { EPI_PLAIN = 0, EPI_QKV = 1, EPI_RESID = 2, EPI_LRELU = 3, EPI_RESID_LRELU = 4 };

template <int EPI>
__global__ __launch_bounds__(256) void gemm_kernel(const float* __restrict__ A,
                                                   const float* __restrict__ W,
                                                   const float* __restrict__ bias,
                                                   const float* __restrict__ resid,
                                                   void* __restrict__ Cv) {
    __shared__ float As[16][68];   // A tile transposed [k][m]
    __shared__ float Bs[16][64];   // W tile [k][n]
    int t = threadIdx.x;
    int tx = t & 15, ty = t >> 4;
    int m0 = blockIdx.x * 64, n0 = blockIdx.y * 64;
    float acc[4][4] = {{0.f}};
    for (int k0 = 0; k0 < kD; k0 += 16) {
        #pragma unroll
        for (int i = 0; i < 4; i++) {
            int flat = t + i * 256;
            int r = flat >> 4, c = flat & 15;
            As[c][r] = A[(size_t)(m0 + r) * kD + k0 + c];
        }
        #pragma unroll
        for (int i = 0; i < 4; i++) {
            int flat = t + i * 256;
            int kk = flat >> 6, n = flat & 63;
            Bs[kk][n] = W[(size_t)(k0 + kk) * kD + n0 + n];
        }
        __syncthreads();
        #pragma unroll
        for (int k = 0; k < 16; k++) {
            float a[4], b2[4];
            #pragma unroll
            for (int i = 0; i < 4; i++) a[i] = As[k][ty * 4 + i];
            #pragma unroll
            for (int j = 0; j < 4; j++) b2[j] = Bs[k][tx * 4 + j];
            #pragma unroll
            for (int i = 0; i < 4; i++)
                #pragma unroll
                for (int j = 0; j < 4; j++)
                    acc[i][j] = fmaf(a[i], b2[j], acc[i][j]);
        }
        __syncthreads();
    }
    #pragma unroll
    for (int i = 0; i < 4; i++) {
        int m = m0 + ty * 4 + i;
        #pragma unroll
        for (int j = 0; j < 4; j++) {
            int n = n0 + tx * 4 + j;
            float v = acc[i][j] + bias[n];
            if (EPI == EPI_QKV) {
                // scatter to (B,H,N,DK) as bf16
                int b = m >> 9, nr = m & 511;
                int hh = n >> 5, dk = n & 31;
                ((bf16*)Cv)[(((size_t)(b * kH + hh)) * kN + nr) * kDK + dk] = bf16(v);
            } else if (EPI == EPI_RESID) {
                ((float*)Cv)[(size_t)m * kD + n] = resid[(size_t)m * kD + n] + v;
            } else if (EPI == EPI_LRELU) {
                ((float*)Cv)[(size_t)m * kD + n] = v > 0.f ? v : 0.1f * v;
            } else if (EPI == EPI_RESID_LRELU) {
                float lv = v > 0.f ? v : 0.1f * v;
                ((float*)Cv)[(size_t)m * kD + n] = resid[(size_t)m * kD + n] + lv;
            } else {
                ((float*)Cv)[(size_t)m * kD + n] = v;
            }
        }
    }
}

// ---------------- MFMA attention --------------------------------------------
// One block per (b, h, 64 q-rows). 4 waves, each owns 16 q rows.
// scores (16x512) via 32 MFMAs; register softmax; P -> LDS transpose (chunked);
// att = (0.3*softmax(S))@V + pc@V via paired MFMA accumulation.
__global__ __launch_bounds__(256, 2) void attn_mfma(const bf16* __restrict__ qb,
                                                    const bf16* __restrict__ kb,
                                                    const bf16* __restrict__ vb,
                                                    const bf16* __restrict__ pcb,
                                                    const int* __restrict__ mask,
                                                    float* __restrict__ att) {
    // V packed in B-fragment order: Vf[((kt*2+dt)*64 + lane)*8 + j]
    __shared__ __align__(16) bf16 Vf[16 * 2 * 64 * 8];       // 32 KB
    __shared__ __align__(16) bf16 Pbuf[4][16][136];          // 17 KB (padded rows)

    int blk = blockIdx.x;
    int qt = blk & 7;               // 8 q-tiles of 64 rows
    int bh = blk >> 3;
    int b = bh >> 3;
    int h = bh & 7;
    int t = threadIdx.x;
    int lane = t & 63, w = t >> 6;
    int g = lane >> 4, li = lane & 15;

    // ---- stage V into fragment layout (coalesced global reads) ----
    {
        const float4* vsrc4 = (const float4*)(vb + (size_t)bh * kN * kDK);
        #pragma unroll
        for (int it = 0; it < 8; it++) {
            int idx = t + it * 256;            // one float4 = 8 bf16
            float4 raw = vsrc4[idx];
            union { float4 f; bf16 hh[8]; } u; u.f = raw;
            int f0 = idx * 8;
            int n = f0 >> 5, dk0 = f0 & 31;
            int kt = n >> 5, j = n & 7, gsl = (n >> 3) & 3;
            #pragma unroll
            for (int e = 0; e < 8; e++) {
                int dk = dk0 + e;
                int dt = dk >> 4;
                int lsl = (gsl << 4) | (dk & 15);
                Vf[((((kt << 1) | dt) << 6) | lsl) * 8 + j] = u.hh[e];
            }
        }
    }
    __syncthreads();

    // ---- scores: S = Q @ K^T (one wave: 16 q-rows x 512 cols) ----
    const bf16* qrow = qb + ((size_t)bh * kN + qt * 64 + w * 16 + li) * kDK + g * 8;
    short8 aQ = *(const short8*)qrow;
    const bf16* kbase = kb + (size_t)bh * kN * kDK;
    const int* mb = mask + b * kN;
    unsigned mbits = 0;
    #pragma unroll
    for (int tt = 0; tt < 32; tt++)
        mbits |= (unsigned)(mb[tt * 16 + li] != 0) << tt;

    floatx4 s[32];
    floatx4 zero = {0.f, 0.f, 0.f, 0.f};
    #pragma unroll
    for (int tt = 0; tt < 32; tt++) {
        short8 bK = *(const short8*)(kbase + (size_t)(tt * 16 + li) * kDK + g * 8);
        s[tt] = __builtin_amdgcn_mfma_f32_16x16x32_bf16(aQ, bK, zero, 0, 0, 0);
    }

    const float scale = 0.17677669529663689f;  // 1/sqrt(32)
    #pragma unroll
    for (int tt = 0; tt < 32; tt++) {
        bool mm = (mbits >> tt) & 1;
        #pragma unroll
        for (int r = 0; r < 4; r++)
            s[tt][r] = mm ? s[tt][r] * scale : -1e12f;
    }

    // ---- softmax per row (row = g*4 + r; cols spread over li and tt) ----
    #pragma unroll
    for (int r = 0; r < 4; r++) {
        float mx = s[0][r];
        #pragma unroll
        for (int tt = 1; tt < 32; tt++) mx = fmaxf(mx, s[tt][r]);
        #pragma unroll
        for (int o = 1; o < 16; o <<= 1) mx = fmaxf(mx, __shfl_xor(mx, o, 64));
        float sum = 0.f;
        #pragma unroll
        for (int tt = 0; tt < 32; tt++) {
            float e = __expf(s[tt][r] - mx);
            s[tt][r] = e;
            sum += e;
        }
        #pragma unroll
        for (int o = 1; o < 16; o <<= 1) sum += __shfl_xor(sum, o, 64);
        float inv = 0.3f / sum;
        #pragma unroll
        for (int tt = 0; tt < 32; tt++) s[tt][r] *= inv;
    }

    // ---- PV: att_rows = P@V + pc@V, chunked transpose through LDS ----
    bf16* pb = &Pbuf[w][0][0];
    const bf16* pcrow = pcb + ((size_t)b * kN + qt * 64 + w * 16) * kN;
    floatx4 accA0 = zero, accA1 = zero, accB0 = zero, accB1 = zero;
    #pragma unroll
    for (int c = 0; c < 4; c++) {
        // write 8 tiles of this chunk into per-wave LDS (C-layout -> [row][k])
        #pragma unroll
        for (int ttl = 0; ttl < 8; ttl++) {
            int tt = c * 8 + ttl;
            int kcol = ttl * 16 + li;
            #pragma unroll
            for (int r = 0; r < 4; r++)
                pb[(g * 4 + r) * 136 + kcol] = bf16(s[tt][r]);
        }
        // consume: 4 k-tiles of 32
        #pragma unroll
        for (int k2 = 0; k2 < 4; k2++) {
            int ktile = c * 4 + k2;
            short8 aP = *(const short8*)(pb + li * 136 + k2 * 32 + g * 8);
            short8 aC = *(const short8*)(pcrow + (size_t)li * kN + c * 128 + k2 * 32 + g * 8);
            short8 bV0 = *(const short8*)(&Vf[((ktile * 2 + 0) * 64 + lane) * 8]);
            short8 bV1 = *(const short8*)(&Vf[((ktile * 2 + 1) * 64 + lane) * 8]);
            accA0 = __builtin_amdgcn_mfma_f32_16x16x32_bf16(aP, bV0, accA0, 0, 0, 0);
            accA1 = __builtin_amdgcn_mfma_f32_16x16x32_bf16(aP, bV1, accA1, 0, 0, 0);
            accB0 = __builtin_amdgcn_mfma_f32_16x16x32_bf16(aC, bV0, accB0, 0, 0, 0);
            accB1 = __builtin_amdgcn_mfma_f32_16x16x32_bf16(aC, bV1, accB1, 0, 0, 0);
        }
    }

    // ---- epilogue: att[b, q, h*32 + d] (fp32) ----
    #pragma unroll
    for (int r = 0; r < 4; r++) {
        size_t row = (size_t)b * kN + qt * 64 + w * 16 + g * 4 + r;
        float* arow = att + row * kD + h * kDK;
        arow[li]      = accA0[r] + accB0[r];
        arow[16 + li] = accA1[r] + accB1[r];
    }
}

// ---------------- host launcher --------------------------------------------
extern "C" void kernel_launch(void* const* d_in, const int* in_sizes, int n_in,
                              void* d_out, int out_size, void* d_ws, size_t ws_size,
                              hipStream_t stream) {
    const float* x    = (const float*)d_in[0];
    const int*   mask = (const int*)d_in[1];
    const float* adj  = (const float*)d_in[2];
    const float* dist = (const float*)d_in[3];
    // d_in[4] = edges_att (unused by reference)
    const float* Wq = (const float*)d_in[5];  const float* bq = (const float*)d_in[6];
    const float* Wk = (const float*)d_in[7];  const float* bk = (const float*)d_in[8];
    const float* Wv = (const float*)d_in[9];  const float* bv = (const float*)d_in[10];
    const float* Wo = (const float*)d_in[11]; const float* bo = (const float*)d_in[12];
    const float* Wf1 = (const float*)d_in[13]; const float* bf1 = (const float*)d_in[14];
    const float* Wf2 = (const float*)d_in[15]; const float* bf2 = (const float*)d_in[16];
    const float* ln1a = (const float*)d_in[17]; const float* ln1b = (const float*)d_in[18];
    const float* ln2a = (const float*)d_in[19]; const float* ln2b = (const float*)d_in[20];
    const float* lnfa = (const float*)d_in[21]; const float* lnfb = (const float*)d_in[22];

    const size_t rows = (size_t)kB * kN;          // 8192
    const size_t actN = rows * kD;                // 2,097,152 elems

    char* wsb = (char*)d_ws;
    bf16*  pcb  = (bf16*)wsb;                       wsb += (size_t)kB * kN * kN * sizeof(bf16);
    float* xc   = (float*)wsb;                      wsb += actN * sizeof(float);
    float* h    = (float*)wsb;                      wsb += actN * sizeof(float);
    float* h2   = (float*)wsb;                      wsb += actN * sizeof(float);
    float* attb = (float*)wsb;                      wsb += actN * sizeof(float);
    bf16*  qbuf = (bf16*)wsb;                       wsb += actN * sizeof(bf16);
    bf16*  kbuf = (bf16*)wsb;                       wsb += actN * sizeof(bf16);
    bf16*  vbuf = (bf16*)wsb;                       wsb += actN * sizeof(bf16);

    hipMemcpyAsync(xc, x, actN * sizeof(float), hipMemcpyDeviceToDevice, stream);
    pc_kernel<<<kB * kN, 256, 0, stream>>>(adj, dist, mask, pcb);

    dim3 gg(128, 4);  // M/64 x 256/64
    for (int i = 0; i < kL; i++) {
        const size_t wOff = (size_t)i * kD * kD;
        const size_t bOff = (size_t)i * kD;
        ln_kernel<<<rows, 256, 0, stream>>>(xc, ln1a + bOff, ln1b + bOff, h);
        gemm_kernel<EPI_QKV><<<gg, 256, 0, stream>>>(h, Wq + wOff, bq + bOff, nullptr, qbuf);
        gemm_kernel<EPI_QKV><<<gg, 256, 0, stream>>>(h, Wk + wOff, bk + bOff, nullptr, kbuf);
        gemm_kernel<EPI_QKV><<<gg, 256, 0, stream>>>(h, Wv + wOff, bv + bOff, nullptr, vbuf);
        attn_mfma<<<kB * kH * (kN / 64), 256, 0, stream>>>(qbuf, kbuf, vbuf, pcb, mask, attb);
        gemm_kernel<EPI_RESID><<<gg, 256, 0, stream>>>(attb, Wo + wOff, bo + bOff, xc, xc);
        ln_kernel<<<rows, 256, 0, stream>>>(xc, ln2a + bOff, ln2b + bOff, h);
        gemm_kernel<EPI_LRELU><<<gg, 256, 0, stream>>>(h, Wf1 + wOff, bf1 + bOff, nullptr, h2);
        gemm_kernel<EPI_RESID_LRELU><<<gg, 256, 0, stream>>>(h2, Wf2 + wOff, bf2 + bOff, xc, xc);
    }
    ln_kernel<<<rows, 256, 0, stream>>>(xc, lnfa, lnfb, (float*)d_out);
}

// Round 3
// 463.236 us; speedup vs baseline: 5.6334x; 1.7695x over previous
//
#include <hip/hip_runtime.h>
#include <hip/hip_bf16.h>
#include <math.h>

// Problem constants (from reference)
constexpr int kB  = 16;
constexpr int kN  = 512;
constexpr int kD  = 256;
constexpr int kH  = 8;
constexpr int kDK = 32;
constexpr int kL  = 4;

using bf16 = __hip_bfloat16;
using short8 = __attribute__((ext_vector_type(8))) short;   // 8 bf16 = 4 VGPR
using floatx4 = __attribute__((ext_vector_type(4))) float;  // MFMA C/D frag

// ---------------- block reduction helpers (256 threads = 4 waves) ----------
__device__ __forceinline__ float blockReduceSum(float v, float* sh) {
    #pragma unroll
    for (int o = 32; o > 0; o >>= 1) v += __shfl_down(v, o, 64);
    int lane = threadIdx.x & 63, w = threadIdx.x >> 6;
    __syncthreads();
    if (lane == 0) sh[w] = v;
    __syncthreads();
    return sh[0] + sh[1] + sh[2] + sh[3];
}

__device__ __forceinline__ float blockReduceMax(float v, float* sh) {
    #pragma unroll
    for (int o = 32; o > 0; o >>= 1) v = fmaxf(v, __shfl_down(v, o, 64));
    int lane = threadIdx.x & 63, w = threadIdx.x >> 6;
    __syncthreads();
    if (lane == 0) sh[w] = v;
    __syncthreads();
    return fmaxf(fmaxf(sh[0], sh[1]), fmaxf(sh[2], sh[3]));
}

// ---------------- weight transpose+convert: W[k][n] fp32 -> Wt[n][k] bf16 ---
// 24 matrices (L x {q,k,v,o,f1,f2}); q/k/v packed into wqkv[L][768][256]
__global__ __launch_bounds__(256) void wconv_kernel(const float* __restrict__ Wq,
                                                    const float* __restrict__ Wk,
                                                    const float* __restrict__ Wv,
                                                    const float* __restrict__ Wo,
                                                    const float* __restrict__ Wf1,
                                                    const float* __restrict__ Wf2,
                                                    bf16* __restrict__ wqkv,
                                                    bf16* __restrict__ wo,
                                                    bf16* __restrict__ wf1,
                                                    bf16* __restrict__ wf2) {
    __shared__ float tile[32][33];
    int bid = blockIdx.x;            // 24 * 64
    int mat = bid >> 6;
    int t6 = bid & 63;
    int tr = t6 >> 3, tc = t6 & 7;   // src tile (k-tile, n-tile)
    int layer = mat / 6, slot = mat % 6;
    const float* src =
        slot == 0 ? Wq : slot == 1 ? Wk : slot == 2 ? Wv :
        slot == 3 ? Wo : slot == 4 ? Wf1 : Wf2;
    src += (size_t)layer * kD * kD;
    bf16* dst;
    if (slot < 3) dst = wqkv + ((size_t)layer * 768 + slot * 256) * kD;
    else dst = (slot == 3 ? wo : slot == 4 ? wf1 : wf2) + (size_t)layer * kD * kD;
    int t = threadIdx.x;
    int r = t >> 5, c = t & 31;      // r 0..7
    #pragma unroll
    for (int i = 0; i < 4; i++)
        tile[r + i * 8][c] = src[(size_t)(tr * 32 + r + i * 8) * kD + tc * 32 + c];
    __syncthreads();
    #pragma unroll
    for (int i = 0; i < 4; i++)
        dst[(size_t)(tc * 32 + r + i * 8) * kD + tr * 32 + c] = bf16(tile[c][r + i * 8]);
}

// ---------------- bias concat for QKV ---------------------------------------
__global__ __launch_bounds__(256) void bcat_kernel(const float* __restrict__ bq,
                                                   const float* __restrict__ bk,
                                                   const float* __restrict__ bv,
                                                   float* __restrict__ bcat) {
    int idx = blockIdx.x * 256 + threadIdx.x;    // 4*768
    int layer = idx / 768, j = idx % 768;
    const float* s = j < 256 ? bq : j < 512 ? bk : bv;
    bcat[idx] = s[layer * 256 + (j & 255)];
}

// ---------------- pc = 0.3*softmax(mask? -dist : -inf) + 0.4*adj/rowsum ----
__global__ __launch_bounds__(256) void pc_kernel(const float* __restrict__ adj,
                                                 const float* __restrict__ dist,
                                                 const int* __restrict__ mask,
                                                 bf16* __restrict__ pcb) {
    __shared__ float sh[4];
    int row = blockIdx.x;            // b*kN + q
    int b = row >> 9;
    int t = threadIdx.x;
    const float* dr = dist + (size_t)row * kN;
    const float* ar = adj + (size_t)row * kN;
    const int* mr = mask + b * kN;
    float d0 = dr[t], d1 = dr[t + 256];
    float a0 = ar[t], a1 = ar[t + 256];
    int m0 = mr[t], m1 = mr[t + 256];
    float s0 = m0 ? -d0 : -INFINITY;
    float s1 = m1 ? -d1 : -INFINITY;
    float mx = blockReduceMax(fmaxf(s0, s1), sh);
    float e0 = __expf(s0 - mx);
    float e1 = __expf(s1 - mx);
    float sum  = blockReduceSum(e0 + e1, sh);
    float asum = blockReduceSum(a0 + a1, sh);
    float w_d = 0.3f / sum;
    float w_a = 0.4f / (asum + 1e-6f);
    bf16* pr = pcb + (size_t)row * kN;
    pr[t]       = bf16(e0 * w_d + a0 * w_a);
    pr[t + 256] = bf16(e1 * w_d + a1 * w_a);
}

// ---------------- LayerNorm (ddof=1, eps added to std) ---------------------
template <typename OT>
__global__ __launch_bounds__(256) void ln_kernel(const float* __restrict__ x,
                                                 const float* __restrict__ ga,
                                                 const float* __restrict__ gb,
                                                 OT* __restrict__ y) {
    __shared__ float sh[4];
    int row = blockIdx.x, t = threadIdx.x;
    float v = x[(size_t)row * kD + t];
    float m = blockReduceSum(v, sh) * (1.0f / kD);
    float dd = v - m;
    float var = blockReduceSum(dd * dd, sh) * (1.0f / (kD - 1));
    float s = sqrtf(var);
    y[(size_t)row * kD + t] = OT(ga[t] * dd / (s + 1e-6f) + gb[t]);
}

// ---------------- bf16 MFMA GEMM: C[M,N] = A[M,256] @ Wt[N,256]^T + bias ----
// 128x64 tile, 4 waves; wave w owns rows w*32..w*32+31 x all 64 cols.
enum { EPI_QKV = 0, EPI_RESID = 1, EPI_LRELU = 2, EPI_RESID_LRELU = 3 };

template <int EPI>
__global__ __launch_bounds__(256) void gemm_mfma(const bf16* __restrict__ A,
                                                 const bf16* __restrict__ Wt,
                                                 const float* __restrict__ bias,
                                                 const float* __restrict__ resid,
                                                 void* __restrict__ Cv) {
    __shared__ __align__(16) bf16 As[128][40];   // pad 40: frag reads 2-way (free)
    __shared__ __align__(16) bf16 Bs[64][40];
    int t = threadIdx.x;
    int m0 = blockIdx.x * 128, n0 = blockIdx.y * 64;
    int lane = t & 63, w = t >> 6, g = lane >> 4, li = lane & 15;
    floatx4 zero = {0.f, 0.f, 0.f, 0.f};
    floatx4 acc[2][4];
    #pragma unroll
    for (int i = 0; i < 2; i++)
        #pragma unroll
        for (int j = 0; j < 4; j++) acc[i][j] = zero;

    for (int k0 = 0; k0 < kD; k0 += 32) {
        int kc = t & 3;
        int r0 = t >> 2;
        *(short8*)&As[r0][kc * 8] =
            *(const short8*)(A + (size_t)(m0 + r0) * kD + k0 + kc * 8);
        *(short8*)&As[r0 + 64][kc * 8] =
            *(const short8*)(A + (size_t)(m0 + r0 + 64) * kD + k0 + kc * 8);
        *(short8*)&Bs[r0][kc * 8] =
            *(const short8*)(Wt + (size_t)(n0 + r0) * kD + k0 + kc * 8);
        __syncthreads();
        short8 af0 = *(const short8*)&As[w * 32 + li][g * 8];
        short8 af1 = *(const short8*)&As[w * 32 + 16 + li][g * 8];
        #pragma unroll
        for (int ct = 0; ct < 4; ct++) {
            short8 bfr = *(const short8*)&Bs[ct * 16 + li][g * 8];
            acc[0][ct] = __builtin_amdgcn_mfma_f32_16x16x32_bf16(af0, bfr, acc[0][ct], 0, 0, 0);
            acc[1][ct] = __builtin_amdgcn_mfma_f32_16x16x32_bf16(af1, bfr, acc[1][ct], 0, 0, 0);
        }
        __syncthreads();
    }

    #pragma unroll
    for (int rt = 0; rt < 2; rt++) {
        #pragma unroll
        for (int ct = 0; ct < 4; ct++) {
            #pragma unroll
            for (int rr = 0; rr < 4; rr++) {
                int m = m0 + w * 32 + rt * 16 + g * 4 + rr;
                int n = n0 + ct * 16 + li;
                float v = acc[rt][ct][rr] + bias[n];
                if constexpr (EPI == EPI_QKV) {
                    int j = n >> 8, nn = n & 255;
                    int b = m >> 9, nr = m & 511;
                    int hh = nn >> 5, dk = nn & 31;
                    ((bf16*)Cv)[(size_t)j * (kB * kN * kD) +
                                (((size_t)(b * kH + hh)) * kN + nr) * kDK + dk] = bf16(v);
                } else if constexpr (EPI == EPI_RESID) {
                    ((float*)Cv)[(size_t)m * kD + n] = resid[(size_t)m * kD + n] + v;
                } else if constexpr (EPI == EPI_LRELU) {
                    ((bf16*)Cv)[(size_t)m * kD + n] = bf16(v > 0.f ? v : 0.1f * v);
                } else {
                    float lv = v > 0.f ? v : 0.1f * v;
                    ((float*)Cv)[(size_t)m * kD + n] = resid[(size_t)m * kD + n] + lv;
                }
            }
        }
    }
}

// ---------------- MFMA attention --------------------------------------------
__global__ __launch_bounds__(256, 2) void attn_mfma(const bf16* __restrict__ qb,
                                                    const bf16* __restrict__ kb,
                                                    const bf16* __restrict__ vb,
                                                    const bf16* __restrict__ pcb,
                                                    const int* __restrict__ mask,
                                                    bf16* __restrict__ att) {
    __shared__ __align__(16) bf16 Vf[16 * 2 * 64 * 8];       // 32 KB
    __shared__ __align__(16) bf16 Pbuf[4][16][136];          // 17 KB

    int blk = blockIdx.x;
    int qt = blk & 7;
    int bh = blk >> 3;
    int b = bh >> 3;
    int h = bh & 7;
    int t = threadIdx.x;
    int lane = t & 63, w = t >> 6;
    int g = lane >> 4, li = lane & 15;

    {
        const float4* vsrc4 = (const float4*)(vb + (size_t)bh * kN * kDK);
        #pragma unroll
        for (int it = 0; it < 8; it++) {
            int idx = t + it * 256;
            float4 raw = vsrc4[idx];
            union { float4 f; bf16 hh[8]; } u; u.f = raw;
            int f0 = idx * 8;
            int n = f0 >> 5, dk0 = f0 & 31;
            int kt = n >> 5, j = n & 7, gsl = (n >> 3) & 3;
            #pragma unroll
            for (int e = 0; e < 8; e++) {
                int dk = dk0 + e;
                int dt = dk >> 4;
                int lsl = (gsl << 4) | (dk & 15);
                Vf[((((kt << 1) | dt) << 6) | lsl) * 8 + j] = u.hh[e];
            }
        }
    }
    __syncthreads();

    const bf16* qrow = qb + ((size_t)bh * kN + qt * 64 + w * 16 + li) * kDK + g * 8;
    short8 aQ = *(const short8*)qrow;
    const bf16* kbase = kb + (size_t)bh * kN * kDK;
    const int* mb = mask + b * kN;
    unsigned mbits = 0;
    #pragma unroll
    for (int tt = 0; tt < 32; tt++)
        mbits |= (unsigned)(mb[tt * 16 + li] != 0) << tt;

    floatx4 s[32];
    floatx4 zero = {0.f, 0.f, 0.f, 0.f};
    #pragma unroll
    for (int tt = 0; tt < 32; tt++) {
        short8 bK = *(const short8*)(kbase + (size_t)(tt * 16 + li) * kDK + g * 8);
        s[tt] = __builtin_amdgcn_mfma_f32_16x16x32_bf16(aQ, bK, zero, 0, 0, 0);
    }

    const float scale = 0.17677669529663689f;  // 1/sqrt(32)
    #pragma unroll
    for (int tt = 0; tt < 32; tt++) {
        bool mm = (mbits >> tt) & 1;
        #pragma unroll
        for (int r = 0; r < 4; r++)
            s[tt][r] = mm ? s[tt][r] * scale : -1e12f;
    }

    #pragma unroll
    for (int r = 0; r < 4; r++) {
        float mx = s[0][r];
        #pragma unroll
        for (int tt = 1; tt < 32; tt++) mx = fmaxf(mx, s[tt][r]);
        #pragma unroll
        for (int o = 1; o < 16; o <<= 1) mx = fmaxf(mx, __shfl_xor(mx, o, 64));
        float sum = 0.f;
        #pragma unroll
        for (int tt = 0; tt < 32; tt++) {
            float e = __expf(s[tt][r] - mx);
            s[tt][r] = e;
            sum += e;
        }
        #pragma unroll
        for (int o = 1; o < 16; o <<= 1) sum += __shfl_xor(sum, o, 64);
        float inv = 0.3f / sum;
        #pragma unroll
        for (int tt = 0; tt < 32; tt++) s[tt][r] *= inv;
    }

    bf16* pb = &Pbuf[w][0][0];
    const bf16* pcrow = pcb + ((size_t)b * kN + qt * 64 + w * 16) * kN;
    floatx4 accA0 = zero, accA1 = zero, accB0 = zero, accB1 = zero;
    #pragma unroll
    for (int c = 0; c < 4; c++) {
        #pragma unroll
        for (int ttl = 0; ttl < 8; ttl++) {
            int tt = c * 8 + ttl;
            int kcol = ttl * 16 + li;
            #pragma unroll
            for (int r = 0; r < 4; r++)
                pb[(g * 4 + r) * 136 + kcol] = bf16(s[tt][r]);
        }
        #pragma unroll
        for (int k2 = 0; k2 < 4; k2++) {
            int ktile = c * 4 + k2;
            short8 aP = *(const short8*)(pb + li * 136 + k2 * 32 + g * 8);
            short8 aC = *(const short8*)(pcrow + (size_t)li * kN + c * 128 + k2 * 32 + g * 8);
            short8 bV0 = *(const short8*)(&Vf[((ktile * 2 + 0) * 64 + lane) * 8]);
            short8 bV1 = *(const short8*)(&Vf[((ktile * 2 + 1) * 64 + lane) * 8]);
            accA0 = __builtin_amdgcn_mfma_f32_16x16x32_bf16(aP, bV0, accA0, 0, 0, 0);
            accA1 = __builtin_amdgcn_mfma_f32_16x16x32_bf16(aP, bV1, accA1, 0, 0, 0);
            accB0 = __builtin_amdgcn_mfma_f32_16x16x32_bf16(aC, bV0, accB0, 0, 0, 0);
            accB1 = __builtin_amdgcn_mfma_f32_16x16x32_bf16(aC, bV1, accB1, 0, 0, 0);
        }
    }

    #pragma unroll
    for (int r = 0; r < 4; r++) {
        size_t row = (size_t)b * kN + qt * 64 + w * 16 + g * 4 + r;
        bf16* arow = att + row * kD + h * kDK;
        arow[li]      = bf16(accA0[r] + accB0[r]);
        arow[16 + li] = bf16(accA1[r] + accB1[r]);
    }
}

// ---------------- host launcher --------------------------------------------
extern "C" void kernel_launch(void* const* d_in, const int* in_sizes, int n_in,
                              void* d_out, int out_size, void* d_ws, size_t ws_size,
                              hipStream_t stream) {
    const float* x    = (const float*)d_in[0];
    const int*   mask = (const int*)d_in[1];
    const float* adj  = (const float*)d_in[2];
    const float* dist = (const float*)d_in[3];
    const float* Wq = (const float*)d_in[5];  const float* bq = (const float*)d_in[6];
    const float* Wk = (const float*)d_in[7];  const float* bk = (const float*)d_in[8];
    const float* Wv = (const float*)d_in[9];  const float* bv = (const float*)d_in[10];
    const float* Wo = (const float*)d_in[11]; const float* bo = (const float*)d_in[12];
    const float* Wf1 = (const float*)d_in[13]; const float* bf1 = (const float*)d_in[14];
    const float* Wf2 = (const float*)d_in[15]; const float* bf2 = (const float*)d_in[16];
    const float* ln1a = (const float*)d_in[17]; const float* ln1b = (const float*)d_in[18];
    const float* ln2a = (const float*)d_in[19]; const float* ln2b = (const float*)d_in[20];
    const float* lnfa = (const float*)d_in[21]; const float* lnfb = (const float*)d_in[22];

    const size_t rows = (size_t)kB * kN;          // 8192
    const size_t actN = rows * kD;                // 2,097,152 elems

    char* wsb = (char*)d_ws;
    bf16*  pcb   = (bf16*)wsb;  wsb += (size_t)kB * kN * kN * sizeof(bf16);
    float* xc    = (float*)wsb; wsb += actN * sizeof(float);
    bf16*  h     = (bf16*)wsb;  wsb += actN * sizeof(bf16);
    bf16*  h2    = (bf16*)wsb;  wsb += actN * sizeof(bf16);
    bf16*  attb  = (bf16*)wsb;  wsb += actN * sizeof(bf16);
    bf16*  qkvb  = (bf16*)wsb;  wsb += 3 * actN * sizeof(bf16);
    bf16*  wqkv  = (bf16*)wsb;  wsb += (size_t)kL * 768 * kD * sizeof(bf16);
    bf16*  wo_t  = (bf16*)wsb;  wsb += (size_t)kL * kD * kD * sizeof(bf16);
    bf16*  wf1_t = (bf16*)wsb;  wsb += (size_t)kL * kD * kD * sizeof(bf16);
    bf16*  wf2_t = (bf16*)wsb;  wsb += (size_t)kL * kD * kD * sizeof(bf16);
    float* bcat  = (float*)wsb; wsb += (size_t)kL * 768 * sizeof(float);

    hipMemcpyAsync(xc, x, actN * sizeof(float), hipMemcpyDeviceToDevice, stream);
    wconv_kernel<<<24 * 64, 256, 0, stream>>>(Wq, Wk, Wv, Wo, Wf1, Wf2, wqkv, wo_t, wf1_t, wf2_t);
    bcat_kernel<<<kL * 768 / 256, 256, 0, stream>>>(bq, bk, bv, bcat);
    pc_kernel<<<kB * kN, 256, 0, stream>>>(adj, dist, mask, pcb);

    dim3 gQKV(64, 12);   // M/128 x 768/64
    dim3 g256(64, 4);    // M/128 x 256/64
    for (int i = 0; i < kL; i++) {
        const size_t bOff = (size_t)i * kD;
        ln_kernel<bf16><<<rows, 256, 0, stream>>>(xc, ln1a + bOff, ln1b + bOff, h);
        gemm_mfma<EPI_QKV><<<gQKV, 256, 0, stream>>>(h, wqkv + (size_t)i * 768 * kD,
                                                     bcat + (size_t)i * 768, nullptr, qkvb);
        attn_mfma<<<kB * kH * (kN / 64), 256, 0, stream>>>(qkvb, qkvb + actN, qkvb + 2 * actN,
                                                           pcb, mask, attb);
        gemm_mfma<EPI_RESID><<<g256, 256, 0, stream>>>(attb, wo_t + (size_t)i * kD * kD,
                                                       bo + bOff, xc, xc);
        ln_kernel<bf16><<<rows, 256, 0, stream>>>(xc, ln2a + bOff, ln2b + bOff, h);
        gemm_mfma<EPI_LRELU><<<g256, 256, 0, stream>>>(h, wf1_t + (size_t)i * kD * kD,
                                                       bf1 + bOff, nullptr, h2);
        gemm_mfma<EPI_RESID_LRELU><<<g256, 256, 0, stream>>>(h2, wf2_t + (size_t)i * kD * kD,
                                                             bf2 + bOff, xc, xc);
    }
    ln_kernel<float><<<rows, 256, 0, stream>>>(xc, lnfa, lnfb, (float*)d_out);
}